// Round 13
// baseline (1436.069 us; speedup 1.0000x reference)
//
#include <hip/hip_runtime.h>
#include <hip/hip_bf16.h>
#include <math.h>

#define NN 100000
#define NE 400000
#define NG 2048
#define BN_EPS 1e-5f
#define NB_SCAN 98   // ceil(NN/1024)

typedef short short8 __attribute__((ext_vector_type(8)));
typedef float f32x4 __attribute__((ext_vector_type(4)));
typedef unsigned short u16x4 __attribute__((ext_vector_type(4)));
typedef unsigned short u16x8 __attribute__((ext_vector_type(8)));

__device__ __forceinline__ float bf2f(unsigned short u){
  union { unsigned u; float f; } x; x.u = ((unsigned)u) << 16; return x.f;
}
__device__ __forceinline__ unsigned short f2bf(float f){
  union { float f; unsigned u; } x; x.f = f;
  unsigned r = x.u + 0x7FFFu + ((x.u >> 16) & 1u);
  return (unsigned short)(r >> 16);
}

__global__ void k_zero(float* p, long n){
  long i = (long)blockIdx.x * blockDim.x + threadIdx.x;
  if (i < n) p[i] = 0.f;
}

__global__ void k_deg(const int* __restrict__ dst, int* __restrict__ deg){
  int e = blockIdx.x * blockDim.x + threadIdx.x;
  if (e < NE) atomicAdd(&deg[dst[e]], 1);
}

// ---- degree-balanced stream assignment (R13) ----
// 64-bin degree histogram -> exclusive scan -> scatter = counting sort of
// vertices by degree. Streams deal perm[] round-robin so per-stream edge
// totals equalize (kills the Poisson straggler tail: slowest block was
// ~+30-40% over mean work).
__global__ void k_hist(const int* __restrict__ deg, int* __restrict__ hist){
  int v = blockIdx.x * blockDim.x + threadIdx.x;
  if (v < NN) atomicAdd(&hist[min(deg[v], 63)], 1);
}

__global__ void k_hscan(int* __restrict__ hist){
  if (threadIdx.x == 0){
    int run = 0;
    for (int i = 0; i < 64; ++i){ int h = hist[i]; hist[i] = run; run += h; }
  }
}

__global__ void k_scatter(const int* __restrict__ deg, int* __restrict__ hist,
                          int* __restrict__ perm){
  int v = blockIdx.x * blockDim.x + threadIdx.x;
  if (v >= NN) return;
  int pos = atomicAdd(&hist[min(deg[v], 63)], 1);
  perm[pos] = v;
}

// ---- parallel exclusive scan of deg -> rowptr/cursor (3 phases) ----
// scan1 also emits dinv = rsqrt(deg+1) (folds former k_dinv launch)
__global__ void k_scan1(const int* __restrict__ deg, int* __restrict__ bsum,
                        float* __restrict__ dinv){
  __shared__ int s[256];
  int b = blockIdx.x, t = threadIdx.x;
  int base = b * 1024;
  int v = 0;
  #pragma unroll
  for (int i = 0; i < 4; ++i){
    int idx = base + t + i * 256;
    if (idx < NN){
      int d = deg[idx];
      v += d;
      dinv[idx] = rsqrtf((float)(d + 1));  // +1 = self loop
    }
  }
  s[t] = v; __syncthreads();
  for (int o = 128; o; o >>= 1){
    if (t < o) s[t] += s[t + o];
    __syncthreads();
  }
  if (t == 0) bsum[b] = s[0];
}

__global__ void k_scan2(const int* __restrict__ bsum, int* __restrict__ boff){
  __shared__ int s[128];
  int t = threadIdx.x;
  int v = (t < NB_SCAN) ? bsum[t] : 0;
  s[t] = v; __syncthreads();
  for (int o = 1; o < 128; o <<= 1){
    int x = (t >= o) ? s[t - o] : 0;
    __syncthreads();
    s[t] += x;
    __syncthreads();
  }
  if (t < NB_SCAN) boff[t] = s[t] - v;  // exclusive block offsets
}

__global__ void k_scan3(const int* __restrict__ deg, const int* __restrict__ boff,
                        int* __restrict__ rowptr, int* __restrict__ cursor){
  __shared__ int s[256];
  int b = blockIdx.x, t = threadIdx.x;
  int base = b * 1024 + t * 4;
  int d[4]; int loc = 0;
  #pragma unroll
  for (int i = 0; i < 4; ++i){
    int idx = base + i;
    d[i] = (idx < NN) ? deg[idx] : 0;
    loc += d[i];
  }
  s[t] = loc; __syncthreads();
  for (int o = 1; o < 256; o <<= 1){
    int x = (t >= o) ? s[t - o] : 0;
    __syncthreads();
    s[t] += x;
    __syncthreads();
  }
  int run = boff[b] + s[t] - loc;
  #pragma unroll
  for (int i = 0; i < 4; ++i){
    int idx = base + i;
    if (idx < NN){ rowptr[idx] = run; cursor[idx] = run; run += d[i]; }
  }
  if (b == NB_SCAN - 1 && t == 255) rowptr[NN] = run;  // = NE
}

// CSR fill: bucket edges by dst; store (src, dinv[src]) fused as int2
__global__ void k_fill(const int* __restrict__ src, const int* __restrict__ dst,
                       const float* __restrict__ dinv, int* __restrict__ cursor,
                       int2* __restrict__ csr){
  int e = blockIdx.x * blockDim.x + threadIdx.x;
  if (e >= NE) return;
  int s = src[e], d = dst[e];
  int p = atomicAdd(&cursor[d], 1);
  csr[p] = make_int2(s, __float_as_int(dinv[s]));
}

// graph boundaries from sorted batch ids; start[NG] = NN
__global__ void k_bounds(const int* __restrict__ batch, int* __restrict__ start){
  int i = blockIdx.x * blockDim.x + threadIdx.x;
  if (i >= NN) return;
  int cur = batch[i];
  int prev = (i == 0) ? -1 : batch[i - 1];
  for (int g = prev + 1; g <= cur; ++g) start[g] = i;
  if (i == NN - 1) for (int g = cur + 1; g <= NG; ++g) start[g] = NN;
}

// Snapshot the 3 bias vectors from d_in into workspace ONCE.
// LESSON (R5): fanning out reads of d_in param vectors across a large grid
// cost ~+180us (k_gemm12 133->219us). d_in params may only be read by tiny
// one-shot kernels; hot kernels read the workspace copy.
__global__ void k_copybias(const float* __restrict__ b0, const float* __restrict__ b1,
                           const float* __restrict__ b2, float* __restrict__ dst){
  int c = threadIdx.x;
  dst[c] = b0[c];
  dst[256 + c] = b1[c];
  dst[512 + c] = b2[c];
}

// Pack weights once: L0 -> bf16 MFMA order (used by gemm0 directly);
// L1/L2 -> f32 MFMA order (rescaled per-layer by k_wprep at runtime).
// Frag f: l=f&63, t=(f>>6)&15, kb=f>>10, q=l>>4, m=l&15;
// element j: W[(kb*32+q*8+j)*256 + t*16+m]  (k = kb*32+q*8+j, n = t*16+m)
__global__ void k_repack3(const float* __restrict__ W0, const float* __restrict__ W1,
                          const float* __restrict__ W2,
                          unsigned short* __restrict__ Wp0,
                          float* __restrict__ Wf32){
  int gid = blockIdx.x * blockDim.x + threadIdx.x;
  if (gid >= 20480) return;
  const float* W; int f; int layer;
  if (gid < 4096){ W = W0; f = gid; layer = 0; }
  else if (gid < 12288){ W = W1; f = gid - 4096; layer = 1; }
  else { W = W2; f = gid - 12288; layer = 2; }
  int l = f & 63, t = (f >> 6) & 15, kb = f >> 10;
  int q = l >> 4, m = l & 15;
  if (layer == 0){
    unsigned short* o = Wp0 + (size_t)f * 8;
    #pragma unroll
    for (int j = 0; j < 8; ++j)
      o[j] = f2bf(W[(size_t)(kb * 32 + q * 8 + j) * 256 + t * 16 + m]);
  } else {
    float* o = Wf32 + (size_t)(layer - 1) * 65536 + (size_t)f * 8;
    #pragma unroll
    for (int j = 0; j < 8; ++j)
      o[j] = W[(size_t)(kb * 32 + q * 8 + j) * 256 + t * 16 + m];
  }
}

// 1024-thread 1-block kernel: BN affine coefs AND (if Wnext) the folded bias
// bias2[n] = sum_k coefB[k]*Wnext[k,n]. k-split 4 ways (t>>8) + LDS reduce.
// Only runtime reader of gamma/beta/W from d_in (R5 lesson: 1 block is fine).
__global__ void k_bncoef(const float* __restrict__ gsum, const float* __restrict__ gsumsq,
                         const float* __restrict__ gamma,
                         const float* __restrict__ beta,
                         const float* __restrict__ Wnext,
                         float* __restrict__ coefA, float* __restrict__ coefB,
                         float* __restrict__ bias2){
  __shared__ float sb[256];
  __shared__ float part[4][256];
  int t = threadIdx.x;
  int c = t & 255, kq = t >> 8;
  if (kq == 0){
    float mu = gsum[c] * (1.f / NN);
    float var = gsumsq[c] * (1.f / NN) - mu * mu;
    float a = gamma[c] / sqrtf(var + BN_EPS);
    coefA[c] = a;
    float b = beta[c] - mu * a;
    coefB[c] = b;
    sb[c] = b;
  }
  if (Wnext == nullptr) return;  // uniform across block
  __syncthreads();
  float acc = 0.f;
  #pragma unroll 8
  for (int k = kq * 64; k < kq * 64 + 64; ++k)
    acc += sb[k] * Wnext[(size_t)k * 256 + c];  // coalesced across c
  part[kq][c] = acc;
  __syncthreads();
  if (kq == 0)
    bias2[c] = part[0][c] + part[1][c] + part[2][c] + part[3][c];
}

// Scale packed f32 weights by coefA[k] -> bf16 MFMA order (BN folded into W).
__global__ void k_wprep(const float* __restrict__ Wf32, const float* __restrict__ coefA,
                        unsigned short* __restrict__ WpS){
  int gid = blockIdx.x * blockDim.x + threadIdx.x;  // frag id, 8192 total
  if (gid >= 8192) return;
  int l = gid & 63, kb = gid >> 10;
  int q = l >> 4;
  int k0 = kb * 32 + q * 8;
  const float* wf = Wf32 + (size_t)gid * 8;
  unsigned short* o = WpS + (size_t)gid * 8;
  #pragma unroll
  for (int j = 0; j < 8; ++j)
    o[j] = f2bf(coefA[k0 + j] * wf[j]);
}

// Stage one 16KB Wp k-slice into LDS, 8-wave cooperative (512-thr blocks):
// wave w stages 2KB at offset w*2048 via 2 x 1KB global_load_lds (width 16).
// LDS dest is wave-uniform base + lane*16 (HW rule); source is per-lane.
#define STAGE_WP8(SRC, KB, BUF) do {                                            \
    const char* gsrc_ = (const char*)(SRC) + (size_t)(KB) * 16384 + wave * 2048 \
                        + lane * 16;                                            \
    char* ldst_ = (char*)(&sW[(BUF)][0]) + wave * 2048;                         \
    _Pragma("unroll")                                                           \
    for (int c_ = 0; c_ < 2; ++c_)                                              \
      __builtin_amdgcn_global_load_lds(                                         \
        (const __attribute__((address_space(1))) void*)(gsrc_ + c_ * 1024),     \
        (__attribute__((address_space(3))) void*)(ldst_ + c_ * 1024),           \
        16, 0, 0);                                                              \
  } while (0)

// Layer 0: B(bf16) = x(f32)[N,128] @ Wp0. Split hi/lo bf16 (x is true f32).
// R11: 128-row tiles, 512 threads (8 waves). R12's nt loads REVERTED (cost
// +20us total: nt bypasses L2 where operands were resident).
__global__ __launch_bounds__(512) void k_gemm0(const float* __restrict__ A,
                                               const unsigned short* __restrict__ Wp,
                                               unsigned short* __restrict__ out){
  const int K = 128;
  __shared__ unsigned short sW[2][8192];  // 2 x 16KB k-slices
  int lane = threadIdx.x & 63;
  int wave = threadIdx.x >> 6;
  int m0 = blockIdx.x * 128 + wave * 16;
  int q = lane >> 4, m = lane & 15;
  int arow = m0 + m;
  bool valid = arow < NN;
  const float* ap = A + (size_t)arow * K + q * 8;
  f32x4 areg[8];
  if (valid){
    #pragma unroll
    for (int kb = 0; kb < 4; ++kb){
      areg[2 * kb]     = *(const f32x4*)(ap + kb * 32);
      areg[2 * kb + 1] = *(const f32x4*)(ap + kb * 32 + 4);
    }
  }
  f32x4 acc[16] = {};
  STAGE_WP8(Wp, 0, 0);
  __syncthreads();
  int buf = 0;
  for (int kb = 0; kb < 4; ++kb){
    if (kb < 3) STAGE_WP8(Wp, kb + 1, buf ^ 1);
    short8 ahi = {}, alo = {};
    if (valid){
      float xs[8] = {areg[2*kb][0], areg[2*kb][1], areg[2*kb][2], areg[2*kb][3],
                     areg[2*kb+1][0], areg[2*kb+1][1], areg[2*kb+1][2], areg[2*kb+1][3]};
      #pragma unroll
      for (int j = 0; j < 8; ++j){
        unsigned short h = f2bf(xs[j]);
        ahi[j] = (short)h;
        alo[j] = (short)f2bf(xs[j] - bf2f(h));
      }
    }
    #pragma unroll
    for (int t = 0; t < 16; ++t){
      short8 b = *(const short8*)(&sW[buf][t * 512 + lane * 8]);
      acc[t] = __builtin_amdgcn_mfma_f32_16x16x32_bf16(ahi, b, acc[t], 0, 0, 0);
      acc[t] = __builtin_amdgcn_mfma_f32_16x16x32_bf16(alo, b, acc[t], 0, 0, 0);
    }
    __syncthreads();  // staging of kb+1 drained; LDS reads of buf done
    buf ^= 1;
  }
  int r0 = m0 + q * 4;
  #pragma unroll
  for (int t = 0; t < 16; ++t)
    #pragma unroll
    for (int r = 0; r < 4; ++r){
      int row = r0 + r;
      if (row < NN) out[(size_t)row * 256 + t * 16 + m] = f2bf(acc[t][r]);
    }
}

// Layers 1-2: B = C(bf16) @ WpS + bias2.  BN affine FOLDED INTO WpS/bias2
// (R7). R11: 128-row tiles, 512 threads. R12's nt loads REVERTED.
__global__ __launch_bounds__(512) void k_gemm12(const unsigned short* __restrict__ A,
                                                const unsigned short* __restrict__ Wp,
                                                const float* __restrict__ bias2,
                                                unsigned short* __restrict__ out){
  const int K = 256;
  __shared__ unsigned short sW[2][8192];  // 2 x 16KB k-slices
  __shared__ float sb2[256];
  if (threadIdx.x < 256) sb2[threadIdx.x] = bias2[threadIdx.x];
  int lane = threadIdx.x & 63;
  int wave = threadIdx.x >> 6;
  int m0 = blockIdx.x * 128 + wave * 16;
  int q = lane >> 4, m = lane & 15;
  int arow = m0 + m;
  bool valid = arow < NN;
  const unsigned short* ap = A + (size_t)arow * K + q * 8;
  short8 areg[8] = {};
  if (valid){
    #pragma unroll
    for (int kb = 0; kb < 8; ++kb) areg[kb] = *(const short8*)(ap + kb * 32);
  }
  f32x4 acc[16] = {};
  STAGE_WP8(Wp, 0, 0);
  __syncthreads();
  int buf = 0;
  for (int kb = 0; kb < 8; ++kb){
    if (kb < 7) STAGE_WP8(Wp, kb + 1, buf ^ 1);
    #pragma unroll
    for (int t = 0; t < 16; ++t){
      short8 b = *(const short8*)(&sW[buf][t * 512 + lane * 8]);
      acc[t] = __builtin_amdgcn_mfma_f32_16x16x32_bf16(areg[kb], b, acc[t], 0, 0, 0);
    }
    __syncthreads();
    buf ^= 1;
  }
  int r0 = m0 + q * 4;
  #pragma unroll
  for (int t = 0; t < 16; ++t){
    float b2 = sb2[t * 16 + m];
    #pragma unroll
    for (int r = 0; r < 4; ++r){
      int row = r0 + r;
      if (row < NN) out[(size_t)row * 256 + t * 16 + m] = f2bf(acc[t][r] + b2);
    }
  }
}

// Pull aggregation + bias + tanh + BN-stats. B bf16 in, C bf16 out.
// Concurrency curve CLOSED: grid=512 FROZEN (peak 1.88 TB/s @ 4096 streams).
// R10: cross-vertex header prefetch (+4us, kept). R12 nt-store: null, reverted.
// R13: DEGREE-BALANCED stream assignment via perm[] (counting-sorted by deg,
// dealt round-robin) -- equalizes per-stream edge totals, trimming the
// Poisson straggler tail (~+30-40% over mean) that sets kernel duration.
__global__ __launch_bounds__(256) void k_gather(const int* __restrict__ perm,
                                                const int* __restrict__ rowptr,
                                                const int2* __restrict__ csr,
                                                const float* __restrict__ dinv,
                                                const unsigned short* __restrict__ B,
                                                const float* __restrict__ bias,
                                                unsigned short* __restrict__ C,
                                                float* __restrict__ gsum,
                                                float* __restrict__ gsumsq){
  __shared__ float lsum[4][256];
  __shared__ float lss[4][256];
  int lane = threadIdx.x & 63;
  int wv = threadIdx.x >> 6;
  int hl = lane & 31;
  int c8 = hl * 8;
  int gs = (int)((blockIdx.x * 256 + threadIdx.x) >> 5);  // global half-wave stream id
  int ns = (int)((gridDim.x * 256) >> 5);
  f32x4 bia0 = *(const f32x4*)(bias + c8);
  f32x4 bia1 = *(const f32x4*)(bias + c8 + 4);
  f32x4 s0 = {}, s1 = {}, ss0 = {}, ss1 = {};
  // ---- prologue: prefetch first vertex header ----
  int idx = gs;
  int v_n = 0; float dv_n = 0.f; int e_n = 0, e1_n = 0; u16x8 bv_n = {};
  if (idx < NN){
    v_n = perm[idx];
    dv_n = dinv[v_n];
    e_n = rowptr[v_n];
    e1_n = rowptr[v_n + 1];
    bv_n = *(const u16x8*)(B + (size_t)v_n * 256 + c8);
  }
  while (idx < NN){
    int v = v_n;
    float dv = dv_n;
    int e = e_n, e1 = e1_n;
    u16x8 bv = bv_n;
    int in2 = idx + ns;
    if (in2 < NN){  // issue next header loads; consumed next iteration
      v_n = perm[in2];
      dv_n = dinv[v_n];
      e_n = rowptr[v_n];
      e1_n = rowptr[v_n + 1];
      bv_n = *(const u16x8*)(B + (size_t)v_n * 256 + c8);
    }
    float a[8], a2[8];
    #pragma unroll
    for (int j = 0; j < 8; ++j){ a[j] = dv * bf2f(bv[j]); a2[j] = 0.f; }
    if (e1 - e >= 2){
      int2 Ea = csr[e], Eb = csr[e + 1];
      u16x8 ra = *(const u16x8*)(B + (size_t)Ea.x * 256 + c8);
      u16x8 rb = *(const u16x8*)(B + (size_t)Eb.x * 256 + c8);
      float wa = __int_as_float(Ea.y), wb = __int_as_float(Eb.y);
      e += 2;
      while (e + 1 < e1){
        int2 Ec = csr[e], Ed = csr[e + 1];
        u16x8 rc = *(const u16x8*)(B + (size_t)Ec.x * 256 + c8);
        u16x8 rd = *(const u16x8*)(B + (size_t)Ed.x * 256 + c8);
        #pragma unroll
        for (int j = 0; j < 8; ++j){
          a[j]  += wa * bf2f(ra[j]);
          a2[j] += wb * bf2f(rb[j]);
        }
        ra = rc; rb = rd;
        wa = __int_as_float(Ec.y); wb = __int_as_float(Ed.y);
        e += 2;
      }
      #pragma unroll
      for (int j = 0; j < 8; ++j){
        a[j]  += wa * bf2f(ra[j]);
        a2[j] += wb * bf2f(rb[j]);
      }
    }
    if (e < e1){
      int2 Ee = csr[e];
      u16x8 re = *(const u16x8*)(B + (size_t)Ee.x * 256 + c8);
      float we = __int_as_float(Ee.y);
      #pragma unroll
      for (int j = 0; j < 8; ++j) a[j] += we * bf2f(re[j]);
    }
    u16x8 ct;
    #pragma unroll
    for (int j = 0; j < 8; ++j){
      float bj = (j < 4) ? bia0[j] : bia1[j - 4];
      float t = tanhf(dv * (a[j] + a2[j]) + bj);
      ct[j] = f2bf(t);
      if (j < 4){ s0[j] += t; ss0[j] += t * t; }
      else      { s1[j - 4] += t; ss1[j - 4] += t * t; }
    }
    *(u16x8*)(C + (size_t)v * 256 + c8) = ct;
    idx = in2;
  }
  // lanes l and l+32 hold partial sums for the SAME columns -> combine halves
  #pragma unroll
  for (int j = 0; j < 4; ++j){
    s0[j]  += __shfl_xor(s0[j], 32);
    s1[j]  += __shfl_xor(s1[j], 32);
    ss0[j] += __shfl_xor(ss0[j], 32);
    ss1[j] += __shfl_xor(ss1[j], 32);
  }
  if ((lane >> 5) == 0){
    *(f32x4*)(&lsum[wv][c8])     = s0;
    *(f32x4*)(&lsum[wv][c8 + 4]) = s1;
    *(f32x4*)(&lss[wv][c8])      = ss0;
    *(f32x4*)(&lss[wv][c8 + 4])  = ss1;
  }
  __syncthreads();
  if (wv == 0){
    int c4 = lane * 4;
    f32x4 aa = *(f32x4*)(&lsum[0][c4]);
    f32x4 bb = *(f32x4*)(&lss[0][c4]);
    #pragma unroll
    for (int w2 = 1; w2 < 4; ++w2){
      aa += *(f32x4*)(&lsum[w2][c4]);
      bb += *(f32x4*)(&lss[w2][c4]);
    }
    #pragma unroll
    for (int i = 0; i < 4; ++i){
      atomicAdd(&gsum[c4 + i], aa[i]);
      atomicAdd(&gsumsq[c4 + i], bb[i]);
    }
  }
}

// block per graph (R4 proven shape; R6's wave-per-graph cost +45us): 4 waves
// split rows, lane owns 4 cols via u16x4 (8B) load/row, LDS max/min reduce.
__global__ __launch_bounds__(256) void k_pool(const unsigned short* __restrict__ C,
                                              const int* __restrict__ start,
                                              const float* __restrict__ coefA,
                                              const float* __restrict__ coefB,
                                              float* __restrict__ out){
  __shared__ float smx[4][256];
  __shared__ float smn[4][256];
  int g = blockIdx.x;
  int w = threadIdx.x >> 6, lane = threadIdx.x & 63;
  int c4 = lane * 4;
  int s = start[g], e = start[g + 1];
  float mx[4] = {-INFINITY, -INFINITY, -INFINITY, -INFINITY};
  float mn[4] = { INFINITY,  INFINITY,  INFINITY,  INFINITY};
  for (int row = s + w; row < e; row += 4){
    u16x4 v = *(const u16x4*)(C + (size_t)row * 256 + c4);
    #pragma unroll
    for (int j = 0; j < 4; ++j){
      float f = bf2f(v[j]);
      mx[j] = fmaxf(mx[j], f);
      mn[j] = fminf(mn[j], f);
    }
  }
  #pragma unroll
  for (int j = 0; j < 4; ++j){
    smx[w][c4 + j] = mx[j];
    smn[w][c4 + j] = mn[j];
  }
  __syncthreads();
  if (w == 0){
    #pragma unroll
    for (int j = 0; j < 4; ++j){
      int c = c4 + j;
      float M = fmaxf(fmaxf(smx[0][c], smx[1][c]), fmaxf(smx[2][c], smx[3][c]));
      float m = fminf(fminf(smn[0][c], smn[1][c]), fminf(smn[2][c], smn[3][c]));
      float a = coefA[c], b = coefB[c];
      float r = (a >= 0.f) ? (a * M + b) : (a * m + b);
      out[(size_t)g * 256 + c] = (e > s) ? r : 0.f;
    }
  }
}

extern "C" void kernel_launch(void* const* d_in, const int* in_sizes, int n_in,
                              void* d_out, int out_size, void* d_ws, size_t ws_size,
                              hipStream_t stream){
  const float* x = (const float*)d_in[0];
  const int* eidx = (const int*)d_in[1];
  const int* batch = (const int*)d_in[2];
  const int* src  = eidx;
  const int* dstv = eidx + NE;
  const float* W[3]  = {(const float*)d_in[3],  (const float*)d_in[7],  (const float*)d_in[11]};
  const float* bb[3] = {(const float*)d_in[4],  (const float*)d_in[8],  (const float*)d_in[12]};
  const float* gm[3] = {(const float*)d_in[5],  (const float*)d_in[9],  (const float*)d_in[13]};
  const float* bt[3] = {(const float*)d_in[6],  (const float*)d_in[10], (const float*)d_in[14]};
  float* out = (float*)d_out;

  char* w = (char*)d_ws;
  unsigned short* B = (unsigned short*)w; w += (size_t)NN * 256 * 2;  // 51.2 MB bf16
  unsigned short* C = (unsigned short*)w; w += (size_t)NN * 256 * 2;  // 51.2 MB bf16
  int2* csr = (int2*)w;            w += (size_t)NE * 8;  // fused (src, w)
  // deg, stat, hist are CONTIGUOUS so one k_zero covers all three
  int* deg = (int*)w;              w += (size_t)NN * 4;
  float* stat = (float*)w;         w += (size_t)3 * 512 * 4;  // [L][gsum|gsumsq]
  int* hist = (int*)w;             w += (size_t)64 * 4;       // degree histogram
  float* dinv = (float*)w;         w += (size_t)NN * 4;
  int* rowptr = (int*)w;           w += (size_t)(NN + 4) * 4;
  int* cursor = (int*)w;           w += (size_t)NN * 4;
  int* perm = (int*)w;             w += (size_t)NN * 4;       // degree-sorted vertex ids
  int* bsum = (int*)w;             w += (size_t)128 * 4;
  int* boff = (int*)w;             w += (size_t)128 * 4;
  unsigned short* Wp0 = (unsigned short*)w; w += (size_t)32768 * 2;   // L0 bf16 packed
  float* Wf32 = (float*)w;         w += (size_t)131072 * 4;           // L1,L2 f32 packed
  unsigned short* WpS = (unsigned short*)w; w += (size_t)65536 * 2;   // scaled bf16 packed
  float* coefA = (float*)w;        w += 256 * 4;
  float* coefB = (float*)w;        w += 256 * 4;
  float* bias2 = (float*)w;        w += 256 * 4;
  float* biasws = (float*)w;       w += (size_t)3 * 256 * 4;  // ws copy of conv biases
  int* start = (int*)w;            w += (size_t)(NG + 1) * 4;

  // graph prep (once per call; captured, so every replay re-zeroes stats first)
  k_zero<<<(NN + 1536 + 64 + 255) / 256, 256, 0, stream>>>((float*)deg, NN + 1536 + 64);
  k_deg<<<(NE + 255) / 256, 256, 0, stream>>>(dstv, deg);
  k_hist<<<(NN + 255) / 256, 256, 0, stream>>>(deg, hist);
  k_hscan<<<1, 64, 0, stream>>>(hist);
  k_scatter<<<(NN + 255) / 256, 256, 0, stream>>>(deg, hist, perm);
  k_scan1<<<NB_SCAN, 256, 0, stream>>>(deg, bsum, dinv);
  k_scan2<<<1, 128, 0, stream>>>(bsum, boff);
  k_scan3<<<NB_SCAN, 256, 0, stream>>>(deg, boff, rowptr, cursor);
  k_fill<<<(NE + 255) / 256, 256, 0, stream>>>(src, dstv, dinv, cursor, csr);
  k_bounds<<<(NN + 255) / 256, 256, 0, stream>>>(batch, start);
  k_repack3<<<80, 256, 0, stream>>>(W[0], W[1], W[2], Wp0, Wf32);
  k_copybias<<<1, 256, 0, stream>>>(bb[0], bb[1], bb[2], biasws);

  for (int L = 0; L < 3; ++L){
    float* gsumL = stat + (size_t)L * 512;
    float* gsumsqL = gsumL + 256;
    if (L == 0){
      k_gemm0<<<(NN + 127) / 128, 512, 0, stream>>>(x, Wp0, B);
    } else {
      k_gemm12<<<(NN + 127) / 128, 512, 0, stream>>>(C, WpS, bias2, B);
    }
    k_gather<<<512, 256, 0, stream>>>(perm, rowptr, csr, dinv, B,
                                      biasws + (size_t)L * 256,
                                      C, gsumL, gsumsqL);
    // coefs + folded bias for next layer's GEMM (1 block; only d_in reader)
    k_bncoef<<<1, 1024, 0, stream>>>(gsumL, gsumsqL, gm[L], bt[L],
                                     (L < 2) ? W[L + 1] : nullptr,
                                     coefA, coefB, bias2);
    if (L < 2)
      k_wprep<<<32, 256, 0, stream>>>(Wf32 + (size_t)L * 65536, coefA, WpS);
    k_pool<<<NG, 256, 0, stream>>>(C, start, coefA, coefB,
                                   out + (size_t)L * NG * 256);
  }
}

// Round 14
// 624.101 us; speedup vs baseline: 2.3010x; 2.3010x over previous
//
#include <hip/hip_runtime.h>
#include <hip/hip_bf16.h>
#include <math.h>

#define NN 100000
#define NE 400000
#define NG 2048
#define BN_EPS 1e-5f
#define NB_SCAN 98   // ceil(NN/1024)

typedef short short8 __attribute__((ext_vector_type(8)));
typedef float f32x4 __attribute__((ext_vector_type(4)));
typedef unsigned short u16x4 __attribute__((ext_vector_type(4)));
typedef unsigned short u16x8 __attribute__((ext_vector_type(8)));

__device__ __forceinline__ float bf2f(unsigned short u){
  union { unsigned u; float f; } x; x.u = ((unsigned)u) << 16; return x.f;
}
__device__ __forceinline__ unsigned short f2bf(float f){
  union { float f; unsigned u; } x; x.f = f;
  unsigned r = x.u + 0x7FFFu + ((x.u >> 16) & 1u);
  return (unsigned short)(r >> 16);
}

__global__ void k_zero(float* p, long n){
  long i = (long)blockIdx.x * blockDim.x + threadIdx.x;
  if (i < n) p[i] = 0.f;
}

__global__ void k_deg(const int* __restrict__ dst, int* __restrict__ deg){
  int e = blockIdx.x * blockDim.x + threadIdx.x;
  if (e < NE) atomicAdd(&deg[dst[e]], 1);
}

// ---- degree-balanced stream assignment (R13/R14) ----
// Counting sort of vertices by degree, dealt round-robin to streams ->
// equalizes per-stream edge totals (trims the straggler tail).
// R14: contention-free two-level build. R13's naive version aimed 200K
// global atomics at 64 addresses -> 755us of serialization (LESSON: never
// point >1K atomics at <100 addresses; pre-aggregate in LDS).
__global__ void k_hist(const int* __restrict__ deg, int* __restrict__ gbin,
                       int* __restrict__ blockbase){
  __shared__ int h[64];
  int b = blockIdx.x, t = threadIdx.x;
  if (t < 64) h[t] = 0;
  __syncthreads();
  #pragma unroll
  for (int i = 0; i < 4; ++i){
    int v = b * 1024 + t + i * 256;
    if (v < NN) atomicAdd(&h[min(deg[v], 63)], 1);  // LDS atomics: fast
  }
  __syncthreads();
  if (t < 64) blockbase[t * NB_SCAN + b] = atomicAdd(&gbin[t], h[t]);  // 98/bin
}

__global__ void k_hscan(int* __restrict__ gbin, int* __restrict__ binstart){
  if (threadIdx.x == 0){
    int run = 0;
    for (int i = 0; i < 64; ++i){ binstart[i] = run; run += gbin[i]; }
  }
}

__global__ void k_scatter(const int* __restrict__ deg, const int* __restrict__ binstart,
                          const int* __restrict__ blockbase, int* __restrict__ perm){
  __shared__ int h[64];
  int b = blockIdx.x, t = threadIdx.x;
  if (t < 64) h[t] = 0;
  __syncthreads();
  #pragma unroll
  for (int i = 0; i < 4; ++i){
    int v = b * 1024 + t + i * 256;
    if (v < NN){
      int bin = min(deg[v], 63);
      int r = atomicAdd(&h[bin], 1);  // local rank within this block's slice
      perm[binstart[bin] + blockbase[bin * NB_SCAN + b] + r] = v;
    }
  }
}

// ---- parallel exclusive scan of deg -> rowptr/cursor (3 phases) ----
// scan1 also emits dinv = rsqrt(deg+1) (folds former k_dinv launch)
__global__ void k_scan1(const int* __restrict__ deg, int* __restrict__ bsum,
                        float* __restrict__ dinv){
  __shared__ int s[256];
  int b = blockIdx.x, t = threadIdx.x;
  int base = b * 1024;
  int v = 0;
  #pragma unroll
  for (int i = 0; i < 4; ++i){
    int idx = base + t + i * 256;
    if (idx < NN){
      int d = deg[idx];
      v += d;
      dinv[idx] = rsqrtf((float)(d + 1));  // +1 = self loop
    }
  }
  s[t] = v; __syncthreads();
  for (int o = 128; o; o >>= 1){
    if (t < o) s[t] += s[t + o];
    __syncthreads();
  }
  if (t == 0) bsum[b] = s[0];
}

__global__ void k_scan2(const int* __restrict__ bsum, int* __restrict__ boff){
  __shared__ int s[128];
  int t = threadIdx.x;
  int v = (t < NB_SCAN) ? bsum[t] : 0;
  s[t] = v; __syncthreads();
  for (int o = 1; o < 128; o <<= 1){
    int x = (t >= o) ? s[t - o] : 0;
    __syncthreads();
    s[t] += x;
    __syncthreads();
  }
  if (t < NB_SCAN) boff[t] = s[t] - v;  // exclusive block offsets
}

__global__ void k_scan3(const int* __restrict__ deg, const int* __restrict__ boff,
                        int* __restrict__ rowptr, int* __restrict__ cursor){
  __shared__ int s[256];
  int b = blockIdx.x, t = threadIdx.x;
  int base = b * 1024 + t * 4;
  int d[4]; int loc = 0;
  #pragma unroll
  for (int i = 0; i < 4; ++i){
    int idx = base + i;
    d[i] = (idx < NN) ? deg[idx] : 0;
    loc += d[i];
  }
  s[t] = loc; __syncthreads();
  for (int o = 1; o < 256; o <<= 1){
    int x = (t >= o) ? s[t - o] : 0;
    __syncthreads();
    s[t] += x;
    __syncthreads();
  }
  int run = boff[b] + s[t] - loc;
  #pragma unroll
  for (int i = 0; i < 4; ++i){
    int idx = base + i;
    if (idx < NN){ rowptr[idx] = run; cursor[idx] = run; run += d[i]; }
  }
  if (b == NB_SCAN - 1 && t == 255) rowptr[NN] = run;  // = NE
}

// CSR fill: bucket edges by dst; store (src, dinv[src]) fused as int2
__global__ void k_fill(const int* __restrict__ src, const int* __restrict__ dst,
                       const float* __restrict__ dinv, int* __restrict__ cursor,
                       int2* __restrict__ csr){
  int e = blockIdx.x * blockDim.x + threadIdx.x;
  if (e >= NE) return;
  int s = src[e], d = dst[e];
  int p = atomicAdd(&cursor[d], 1);
  csr[p] = make_int2(s, __float_as_int(dinv[s]));
}

// graph boundaries from sorted batch ids; start[NG] = NN
__global__ void k_bounds(const int* __restrict__ batch, int* __restrict__ start){
  int i = blockIdx.x * blockDim.x + threadIdx.x;
  if (i >= NN) return;
  int cur = batch[i];
  int prev = (i == 0) ? -1 : batch[i - 1];
  for (int g = prev + 1; g <= cur; ++g) start[g] = i;
  if (i == NN - 1) for (int g = cur + 1; g <= NG; ++g) start[g] = NN;
}

// Snapshot the 3 bias vectors from d_in into workspace ONCE (R5 lesson).
__global__ void k_copybias(const float* __restrict__ b0, const float* __restrict__ b1,
                           const float* __restrict__ b2, float* __restrict__ dst){
  int c = threadIdx.x;
  dst[c] = b0[c];
  dst[256 + c] = b1[c];
  dst[512 + c] = b2[c];
}

// Pack weights once: L0 -> bf16 MFMA order (used by gemm0 directly);
// L1/L2 -> f32 MFMA order (rescaled per-layer by k_wprep at runtime).
__global__ void k_repack3(const float* __restrict__ W0, const float* __restrict__ W1,
                          const float* __restrict__ W2,
                          unsigned short* __restrict__ Wp0,
                          float* __restrict__ Wf32){
  int gid = blockIdx.x * blockDim.x + threadIdx.x;
  if (gid >= 20480) return;
  const float* W; int f; int layer;
  if (gid < 4096){ W = W0; f = gid; layer = 0; }
  else if (gid < 12288){ W = W1; f = gid - 4096; layer = 1; }
  else { W = W2; f = gid - 12288; layer = 2; }
  int l = f & 63, t = (f >> 6) & 15, kb = f >> 10;
  int q = l >> 4, m = l & 15;
  if (layer == 0){
    unsigned short* o = Wp0 + (size_t)f * 8;
    #pragma unroll
    for (int j = 0; j < 8; ++j)
      o[j] = f2bf(W[(size_t)(kb * 32 + q * 8 + j) * 256 + t * 16 + m]);
  } else {
    float* o = Wf32 + (size_t)(layer - 1) * 65536 + (size_t)f * 8;
    #pragma unroll
    for (int j = 0; j < 8; ++j)
      o[j] = W[(size_t)(kb * 32 + q * 8 + j) * 256 + t * 16 + m];
  }
}

// 1024-thread 1-block kernel: BN affine coefs AND (if Wnext) the folded bias
// bias2[n] = sum_k coefB[k]*Wnext[k,n]. k-split 4 ways (t>>8) + LDS reduce.
__global__ void k_bncoef(const float* __restrict__ gsum, const float* __restrict__ gsumsq,
                         const float* __restrict__ gamma,
                         const float* __restrict__ beta,
                         const float* __restrict__ Wnext,
                         float* __restrict__ coefA, float* __restrict__ coefB,
                         float* __restrict__ bias2){
  __shared__ float sb[256];
  __shared__ float part[4][256];
  int t = threadIdx.x;
  int c = t & 255, kq = t >> 8;
  if (kq == 0){
    float mu = gsum[c] * (1.f / NN);
    float var = gsumsq[c] * (1.f / NN) - mu * mu;
    float a = gamma[c] / sqrtf(var + BN_EPS);
    coefA[c] = a;
    float b = beta[c] - mu * a;
    coefB[c] = b;
    sb[c] = b;
  }
  if (Wnext == nullptr) return;  // uniform across block
  __syncthreads();
  float acc = 0.f;
  #pragma unroll 8
  for (int k = kq * 64; k < kq * 64 + 64; ++k)
    acc += sb[k] * Wnext[(size_t)k * 256 + c];  // coalesced across c
  part[kq][c] = acc;
  __syncthreads();
  if (kq == 0)
    bias2[c] = part[0][c] + part[1][c] + part[2][c] + part[3][c];
}

// Scale packed f32 weights by coefA[k] -> bf16 MFMA order (BN folded into W).
__global__ void k_wprep(const float* __restrict__ Wf32, const float* __restrict__ coefA,
                        unsigned short* __restrict__ WpS){
  int gid = blockIdx.x * blockDim.x + threadIdx.x;  // frag id, 8192 total
  if (gid >= 8192) return;
  int l = gid & 63, kb = gid >> 10;
  int q = l >> 4;
  int k0 = kb * 32 + q * 8;
  const float* wf = Wf32 + (size_t)gid * 8;
  unsigned short* o = WpS + (size_t)gid * 8;
  #pragma unroll
  for (int j = 0; j < 8; ++j)
    o[j] = f2bf(coefA[k0 + j] * wf[j]);
}

// Stage one 16KB Wp k-slice into LDS, 8-wave cooperative (512-thr blocks).
#define STAGE_WP8(SRC, KB, BUF) do {                                            \
    const char* gsrc_ = (const char*)(SRC) + (size_t)(KB) * 16384 + wave * 2048 \
                        + lane * 16;                                            \
    char* ldst_ = (char*)(&sW[(BUF)][0]) + wave * 2048;                         \
    _Pragma("unroll")                                                           \
    for (int c_ = 0; c_ < 2; ++c_)                                              \
      __builtin_amdgcn_global_load_lds(                                         \
        (const __attribute__((address_space(1))) void*)(gsrc_ + c_ * 1024),     \
        (__attribute__((address_space(3))) void*)(ldst_ + c_ * 1024),           \
        16, 0, 0);                                                              \
  } while (0)

// Layer 0: B(bf16) = x(f32)[N,128] @ Wp0. Split hi/lo bf16 (x is true f32).
__global__ __launch_bounds__(512) void k_gemm0(const float* __restrict__ A,
                                               const unsigned short* __restrict__ Wp,
                                               unsigned short* __restrict__ out){
  const int K = 128;
  __shared__ unsigned short sW[2][8192];  // 2 x 16KB k-slices
  int lane = threadIdx.x & 63;
  int wave = threadIdx.x >> 6;
  int m0 = blockIdx.x * 128 + wave * 16;
  int q = lane >> 4, m = lane & 15;
  int arow = m0 + m;
  bool valid = arow < NN;
  const float* ap = A + (size_t)arow * K + q * 8;
  f32x4 areg[8];
  if (valid){
    #pragma unroll
    for (int kb = 0; kb < 4; ++kb){
      areg[2 * kb]     = *(const f32x4*)(ap + kb * 32);
      areg[2 * kb + 1] = *(const f32x4*)(ap + kb * 32 + 4);
    }
  }
  f32x4 acc[16] = {};
  STAGE_WP8(Wp, 0, 0);
  __syncthreads();
  int buf = 0;
  for (int kb = 0; kb < 4; ++kb){
    if (kb < 3) STAGE_WP8(Wp, kb + 1, buf ^ 1);
    short8 ahi = {}, alo = {};
    if (valid){
      float xs[8] = {areg[2*kb][0], areg[2*kb][1], areg[2*kb][2], areg[2*kb][3],
                     areg[2*kb+1][0], areg[2*kb+1][1], areg[2*kb+1][2], areg[2*kb+1][3]};
      #pragma unroll
      for (int j = 0; j < 8; ++j){
        unsigned short h = f2bf(xs[j]);
        ahi[j] = (short)h;
        alo[j] = (short)f2bf(xs[j] - bf2f(h));
      }
    }
    #pragma unroll
    for (int t = 0; t < 16; ++t){
      short8 b = *(const short8*)(&sW[buf][t * 512 + lane * 8]);
      acc[t] = __builtin_amdgcn_mfma_f32_16x16x32_bf16(ahi, b, acc[t], 0, 0, 0);
      acc[t] = __builtin_amdgcn_mfma_f32_16x16x32_bf16(alo, b, acc[t], 0, 0, 0);
    }
    __syncthreads();  // staging of kb+1 drained; LDS reads of buf done
    buf ^= 1;
  }
  int r0 = m0 + q * 4;
  #pragma unroll
  for (int t = 0; t < 16; ++t)
    #pragma unroll
    for (int r = 0; r < 4; ++r){
      int row = r0 + r;
      if (row < NN) out[(size_t)row * 256 + t * 16 + m] = f2bf(acc[t][r]);
    }
}

// Layers 1-2: B = C(bf16) @ WpS + bias2.  BN affine FOLDED INTO WpS/bias2.
__global__ __launch_bounds__(512) void k_gemm12(const unsigned short* __restrict__ A,
                                                const unsigned short* __restrict__ Wp,
                                                const float* __restrict__ bias2,
                                                unsigned short* __restrict__ out){
  const int K = 256;
  __shared__ unsigned short sW[2][8192];  // 2 x 16KB k-slices
  __shared__ float sb2[256];
  if (threadIdx.x < 256) sb2[threadIdx.x] = bias2[threadIdx.x];
  int lane = threadIdx.x & 63;
  int wave = threadIdx.x >> 6;
  int m0 = blockIdx.x * 128 + wave * 16;
  int q = lane >> 4, m = lane & 15;
  int arow = m0 + m;
  bool valid = arow < NN;
  const unsigned short* ap = A + (size_t)arow * K + q * 8;
  short8 areg[8] = {};
  if (valid){
    #pragma unroll
    for (int kb = 0; kb < 8; ++kb) areg[kb] = *(const short8*)(ap + kb * 32);
  }
  f32x4 acc[16] = {};
  STAGE_WP8(Wp, 0, 0);
  __syncthreads();
  int buf = 0;
  for (int kb = 0; kb < 8; ++kb){
    if (kb < 7) STAGE_WP8(Wp, kb + 1, buf ^ 1);
    #pragma unroll
    for (int t = 0; t < 16; ++t){
      short8 b = *(const short8*)(&sW[buf][t * 512 + lane * 8]);
      acc[t] = __builtin_amdgcn_mfma_f32_16x16x32_bf16(areg[kb], b, acc[t], 0, 0, 0);
    }
    __syncthreads();
    buf ^= 1;
  }
  int r0 = m0 + q * 4;
  #pragma unroll
  for (int t = 0; t < 16; ++t){
    float b2 = sb2[t * 16 + m];
    #pragma unroll
    for (int r = 0; r < 4; ++r){
      int row = r0 + r;
      if (row < NN) out[(size_t)row * 256 + t * 16 + m] = f2bf(acc[t][r] + b2);
    }
  }
}

// Pull aggregation + bias + tanh + BN-stats. B bf16 in, C bf16 out.
// grid=512 FROZEN (concurrency curve closed, peak @ 4096 streams).
// R10 header prefetch kept. R13/R14: degree-balanced perm round-robin.
__global__ __launch_bounds__(256) void k_gather(const int* __restrict__ perm,
                                                const int* __restrict__ rowptr,
                                                const int2* __restrict__ csr,
                                                const float* __restrict__ dinv,
                                                const unsigned short* __restrict__ B,
                                                const float* __restrict__ bias,
                                                unsigned short* __restrict__ C,
                                                float* __restrict__ gsum,
                                                float* __restrict__ gsumsq){
  __shared__ float lsum[4][256];
  __shared__ float lss[4][256];
  int lane = threadIdx.x & 63;
  int wv = threadIdx.x >> 6;
  int hl = lane & 31;
  int c8 = hl * 8;
  int gs = (int)((blockIdx.x * 256 + threadIdx.x) >> 5);  // global half-wave stream id
  int ns = (int)((gridDim.x * 256) >> 5);
  f32x4 bia0 = *(const f32x4*)(bias + c8);
  f32x4 bia1 = *(const f32x4*)(bias + c8 + 4);
  f32x4 s0 = {}, s1 = {}, ss0 = {}, ss1 = {};
  // ---- prologue: prefetch first vertex header ----
  int idx = gs;
  int v_n = 0; float dv_n = 0.f; int e_n = 0, e1_n = 0; u16x8 bv_n = {};
  if (idx < NN){
    v_n = perm[idx];
    dv_n = dinv[v_n];
    e_n = rowptr[v_n];
    e1_n = rowptr[v_n + 1];
    bv_n = *(const u16x8*)(B + (size_t)v_n * 256 + c8);
  }
  while (idx < NN){
    int v = v_n;
    float dv = dv_n;
    int e = e_n, e1 = e1_n;
    u16x8 bv = bv_n;
    int in2 = idx + ns;
    if (in2 < NN){  // issue next header loads; consumed next iteration
      v_n = perm[in2];
      dv_n = dinv[v_n];
      e_n = rowptr[v_n];
      e1_n = rowptr[v_n + 1];
      bv_n = *(const u16x8*)(B + (size_t)v_n * 256 + c8);
    }
    float a[8], a2[8];
    #pragma unroll
    for (int j = 0; j < 8; ++j){ a[j] = dv * bf2f(bv[j]); a2[j] = 0.f; }
    if (e1 - e >= 2){
      int2 Ea = csr[e], Eb = csr[e + 1];
      u16x8 ra = *(const u16x8*)(B + (size_t)Ea.x * 256 + c8);
      u16x8 rb = *(const u16x8*)(B + (size_t)Eb.x * 256 + c8);
      float wa = __int_as_float(Ea.y), wb = __int_as_float(Eb.y);
      e += 2;
      while (e + 1 < e1){
        int2 Ec = csr[e], Ed = csr[e + 1];
        u16x8 rc = *(const u16x8*)(B + (size_t)Ec.x * 256 + c8);
        u16x8 rd = *(const u16x8*)(B + (size_t)Ed.x * 256 + c8);
        #pragma unroll
        for (int j = 0; j < 8; ++j){
          a[j]  += wa * bf2f(ra[j]);
          a2[j] += wb * bf2f(rb[j]);
        }
        ra = rc; rb = rd;
        wa = __int_as_float(Ec.y); wb = __int_as_float(Ed.y);
        e += 2;
      }
      #pragma unroll
      for (int j = 0; j < 8; ++j){
        a[j]  += wa * bf2f(ra[j]);
        a2[j] += wb * bf2f(rb[j]);
      }
    }
    if (e < e1){
      int2 Ee = csr[e];
      u16x8 re = *(const u16x8*)(B + (size_t)Ee.x * 256 + c8);
      float we = __int_as_float(Ee.y);
      #pragma unroll
      for (int j = 0; j < 8; ++j) a[j] += we * bf2f(re[j]);
    }
    u16x8 ct;
    #pragma unroll
    for (int j = 0; j < 8; ++j){
      float bj = (j < 4) ? bia0[j] : bia1[j - 4];
      float t = tanhf(dv * (a[j] + a2[j]) + bj);
      ct[j] = f2bf(t);
      if (j < 4){ s0[j] += t; ss0[j] += t * t; }
      else      { s1[j - 4] += t; ss1[j - 4] += t * t; }
    }
    *(u16x8*)(C + (size_t)v * 256 + c8) = ct;
    idx = in2;
  }
  // lanes l and l+32 hold partial sums for the SAME columns -> combine halves
  #pragma unroll
  for (int j = 0; j < 4; ++j){
    s0[j]  += __shfl_xor(s0[j], 32);
    s1[j]  += __shfl_xor(s1[j], 32);
    ss0[j] += __shfl_xor(ss0[j], 32);
    ss1[j] += __shfl_xor(ss1[j], 32);
  }
  if ((lane >> 5) == 0){
    *(f32x4*)(&lsum[wv][c8])     = s0;
    *(f32x4*)(&lsum[wv][c8 + 4]) = s1;
    *(f32x4*)(&lss[wv][c8])      = ss0;
    *(f32x4*)(&lss[wv][c8 + 4])  = ss1;
  }
  __syncthreads();
  if (wv == 0){
    int c4 = lane * 4;
    f32x4 aa = *(f32x4*)(&lsum[0][c4]);
    f32x4 bb = *(f32x4*)(&lss[0][c4]);
    #pragma unroll
    for (int w2 = 1; w2 < 4; ++w2){
      aa += *(f32x4*)(&lsum[w2][c4]);
      bb += *(f32x4*)(&lss[w2][c4]);
    }
    #pragma unroll
    for (int i = 0; i < 4; ++i){
      atomicAdd(&gsum[c4 + i], aa[i]);
      atomicAdd(&gsumsq[c4 + i], bb[i]);
    }
  }
}

// block per graph (R4 proven shape): 4 waves split rows, lane owns 4 cols
// via u16x4 (8B) load/row, LDS max/min reduce.
__global__ __launch_bounds__(256) void k_pool(const unsigned short* __restrict__ C,
                                              const int* __restrict__ start,
                                              const float* __restrict__ coefA,
                                              const float* __restrict__ coefB,
                                              float* __restrict__ out){
  __shared__ float smx[4][256];
  __shared__ float smn[4][256];
  int g = blockIdx.x;
  int w = threadIdx.x >> 6, lane = threadIdx.x & 63;
  int c4 = lane * 4;
  int s = start[g], e = start[g + 1];
  float mx[4] = {-INFINITY, -INFINITY, -INFINITY, -INFINITY};
  float mn[4] = { INFINITY,  INFINITY,  INFINITY,  INFINITY};
  for (int row = s + w; row < e; row += 4){
    u16x4 v = *(const u16x4*)(C + (size_t)row * 256 + c4);
    #pragma unroll
    for (int j = 0; j < 4; ++j){
      float f = bf2f(v[j]);
      mx[j] = fmaxf(mx[j], f);
      mn[j] = fminf(mn[j], f);
    }
  }
  #pragma unroll
  for (int j = 0; j < 4; ++j){
    smx[w][c4 + j] = mx[j];
    smn[w][c4 + j] = mn[j];
  }
  __syncthreads();
  if (w == 0){
    #pragma unroll
    for (int j = 0; j < 4; ++j){
      int c = c4 + j;
      float M = fmaxf(fmaxf(smx[0][c], smx[1][c]), fmaxf(smx[2][c], smx[3][c]));
      float m = fminf(fminf(smn[0][c], smn[1][c]), fminf(smn[2][c], smn[3][c]));
      float a = coefA[c], b = coefB[c];
      float r = (a >= 0.f) ? (a * M + b) : (a * m + b);
      out[(size_t)g * 256 + c] = (e > s) ? r : 0.f;
    }
  }
}

extern "C" void kernel_launch(void* const* d_in, const int* in_sizes, int n_in,
                              void* d_out, int out_size, void* d_ws, size_t ws_size,
                              hipStream_t stream){
  const float* x = (const float*)d_in[0];
  const int* eidx = (const int*)d_in[1];
  const int* batch = (const int*)d_in[2];
  const int* src  = eidx;
  const int* dstv = eidx + NE;
  const float* W[3]  = {(const float*)d_in[3],  (const float*)d_in[7],  (const float*)d_in[11]};
  const float* bb[3] = {(const float*)d_in[4],  (const float*)d_in[8],  (const float*)d_in[12]};
  const float* gm[3] = {(const float*)d_in[5],  (const float*)d_in[9],  (const float*)d_in[13]};
  const float* bt[3] = {(const float*)d_in[6],  (const float*)d_in[10], (const float*)d_in[14]};
  float* out = (float*)d_out;

  char* w = (char*)d_ws;
  unsigned short* B = (unsigned short*)w; w += (size_t)NN * 256 * 2;  // 51.2 MB bf16
  unsigned short* C = (unsigned short*)w; w += (size_t)NN * 256 * 2;  // 51.2 MB bf16
  int2* csr = (int2*)w;            w += (size_t)NE * 8;  // fused (src, w)
  // deg, stat, gbin are CONTIGUOUS so one k_zero covers all three
  int* deg = (int*)w;              w += (size_t)NN * 4;
  float* stat = (float*)w;         w += (size_t)3 * 512 * 4;  // [L][gsum|gsumsq]
  int* gbin = (int*)w;             w += (size_t)64 * 4;       // degree bin counts
  int* binstart = (int*)w;         w += (size_t)64 * 4;
  int* blockbase = (int*)w;        w += (size_t)64 * NB_SCAN * 4;
  float* dinv = (float*)w;         w += (size_t)NN * 4;
  int* rowptr = (int*)w;           w += (size_t)(NN + 4) * 4;
  int* cursor = (int*)w;           w += (size_t)NN * 4;
  int* perm = (int*)w;             w += (size_t)NN * 4;       // degree-sorted vertex ids
  int* bsum = (int*)w;             w += (size_t)128 * 4;
  int* boff = (int*)w;             w += (size_t)128 * 4;
  unsigned short* Wp0 = (unsigned short*)w; w += (size_t)32768 * 2;   // L0 bf16 packed
  float* Wf32 = (float*)w;         w += (size_t)131072 * 4;           // L1,L2 f32 packed
  unsigned short* WpS = (unsigned short*)w; w += (size_t)65536 * 2;   // scaled bf16 packed
  float* coefA = (float*)w;        w += 256 * 4;
  float* coefB = (float*)w;        w += 256 * 4;
  float* bias2 = (float*)w;        w += 256 * 4;
  float* biasws = (float*)w;       w += (size_t)3 * 256 * 4;  // ws copy of conv biases
  int* start = (int*)w;            w += (size_t)(NG + 1) * 4;

  // graph prep (once per call; captured, so every replay re-zeroes stats first)
  k_zero<<<(NN + 1536 + 64 + 255) / 256, 256, 0, stream>>>((float*)deg, NN + 1536 + 64);
  k_deg<<<(NE + 255) / 256, 256, 0, stream>>>(dstv, deg);
  k_hist<<<NB_SCAN, 256, 0, stream>>>(deg, gbin, blockbase);
  k_hscan<<<1, 64, 0, stream>>>(gbin, binstart);
  k_scatter<<<NB_SCAN, 256, 0, stream>>>(deg, binstart, blockbase, perm);
  k_scan1<<<NB_SCAN, 256, 0, stream>>>(deg, bsum, dinv);
  k_scan2<<<1, 128, 0, stream>>>(bsum, boff);
  k_scan3<<<NB_SCAN, 256, 0, stream>>>(deg, boff, rowptr, cursor);
  k_fill<<<(NE + 255) / 256, 256, 0, stream>>>(src, dstv, dinv, cursor, csr);
  k_bounds<<<(NN + 255) / 256, 256, 0, stream>>>(batch, start);
  k_repack3<<<80, 256, 0, stream>>>(W[0], W[1], W[2], Wp0, Wf32);
  k_copybias<<<1, 256, 0, stream>>>(bb[0], bb[1], bb[2], biasws);

  for (int L = 0; L < 3; ++L){
    float* gsumL = stat + (size_t)L * 512;
    float* gsumsqL = gsumL + 256;
    if (L == 0){
      k_gemm0<<<(NN + 127) / 128, 512, 0, stream>>>(x, Wp0, B);
    } else {
      k_gemm12<<<(NN + 127) / 128, 512, 0, stream>>>(C, WpS, bias2, B);
    }
    k_gather<<<512, 256, 0, stream>>>(perm, rowptr, csr, dinv, B,
                                      biasws + (size_t)L * 256,
                                      C, gsumL, gsumsqL);
    // coefs + folded bias for next layer's GEMM (1 block; only d_in reader)
    k_bncoef<<<1, 1024, 0, stream>>>(gsumL, gsumsqL, gm[L], bt[L],
                                     (L < 2) ? W[L + 1] : nullptr,
                                     coefA, coefB, bias2);
    if (L < 2)
      k_wprep<<<32, 256, 0, stream>>>(Wf32 + (size_t)L * 65536, coefA, WpS);
    k_pool<<<NG, 256, 0, stream>>>(C, start, coefA, coefB,
                                   out + (size_t)L * NG * 256);
  }
}